// Round 1
// baseline (661.535 us; speedup 1.0000x reference)
//
#include <hip/hip_runtime.h>
#include <hip/hip_bf16.h>

#define NN 10000
#define NE 320000
#define D 256
#define D4 64   // float4 per node row

// ---------------- CSR build (once per call; graph is static across layers) ---

__global__ void hist_kernel(const int* __restrict__ dst, int* __restrict__ cnt, int nE) {
    int e = blockIdx.x * blockDim.x + threadIdx.x;
    if (e < nE) atomicAdd(&cnt[dst[e]], 1);
}

// single-block exclusive scan over NN counts -> rowptr[0..NN]
__global__ void scan_kernel(const int* __restrict__ cnt, int* __restrict__ rowptr, int n) {
    __shared__ int part[256];
    int t = threadIdx.x;
    int chunk = (n + 255) / 256;
    int b = t * chunk;
    int e = b + chunk; if (e > n) e = n;
    int s = 0;
    for (int i = b; i < e; ++i) s += cnt[i];
    part[t] = s;
    __syncthreads();
    if (t == 0) {
        int acc = 0;
        for (int i = 0; i < 256; ++i) { int v = part[i]; part[i] = acc; acc += v; }
    }
    __syncthreads();
    if (b < n) {
        int acc = part[t];
        for (int i = b; i < e; ++i) { rowptr[i] = acc; acc += cnt[i]; }
        if (e == n) rowptr[n] = acc;   // total == nE
    }
}

__global__ void scatter_kernel(const int* __restrict__ dst, const int* __restrict__ rowptr,
                               int* __restrict__ cnt, int* __restrict__ eidx, int nE) {
    int e = blockIdx.x * blockDim.x + threadIdx.x;
    if (e < nE) {
        int d = dst[e];
        int pos = rowptr[d] + atomicAdd(&cnt[d], 1);
        eidx[pos] = e;
    }
}

// ---------------- per-layer kernels -----------------------------------------

// inv[n] = rsqrt(sum(h[n]^2) + 1e-16): one wave per node
__global__ void norm_kernel(const float4* __restrict__ h, float* __restrict__ inv, int n) {
    int wid  = (blockIdx.x * blockDim.x + threadIdx.x) >> 6;
    int lane = threadIdx.x & 63;
    if (wid >= n) return;
    float4 v = h[wid * D4 + lane];
    float s = v.x * v.x + v.y * v.y + v.z * v.z + v.w * v.w;
    #pragma unroll
    for (int o = 32; o; o >>= 1) s += __shfl_xor(s, o);
    if (lane == 0) inv[wid] = rsqrtf(s + 1e-16f);
}

// ex[e] = exp(beta * cos(h[src], h[dst])): one wave per edge
__global__ void edge_kernel(const float4* __restrict__ h, const float* __restrict__ inv,
                            const int* __restrict__ src, const int* __restrict__ dst,
                            const float* __restrict__ betas, int layer,
                            float* __restrict__ ex, int nE) {
    int e    = (blockIdx.x * blockDim.x + threadIdx.x) >> 6;
    int lane = threadIdx.x & 63;
    if (e >= nE) return;
    int s = src[e], d = dst[e];
    float4 a = h[s * D4 + lane];
    float4 b = h[d * D4 + lane];
    float p = a.x * b.x + a.y * b.y + a.z * b.z + a.w * b.w;
    #pragma unroll
    for (int o = 32; o; o >>= 1) p += __shfl_xor(p, o);
    if (lane == 0) {
        float c = p * inv[s] * inv[d];
        ex[e] = __expf(betas[layer] * c);
    }
}

// out[n] = relu( sum_e alpha_e * h[src[e]] ), alpha = ex/denom: one wave per node
__global__ void agg_kernel(const float4* __restrict__ h, const float* __restrict__ ex,
                           const int* __restrict__ rowptr, const int* __restrict__ eidx,
                           const int* __restrict__ src, float4* __restrict__ out, int n) {
    int wid  = (blockIdx.x * blockDim.x + threadIdx.x) >> 6;
    int lane = threadIdx.x & 63;
    if (wid >= n) return;
    int beg = rowptr[wid], end = rowptr[wid + 1];

    // denominator: lanes sum ex over this node's in-edges
    float dsum = 0.f;
    for (int i = beg + lane; i < end; i += 64) dsum += ex[eidx[i]];
    #pragma unroll
    for (int o = 32; o; o >>= 1) dsum += __shfl_xor(dsum, o);
    float invd = 1.f / (dsum + 1e-16f);

    float4 acc = make_float4(0.f, 0.f, 0.f, 0.f);
    for (int i = beg; i < end; ++i) {
        int e = eidx[i];
        float w = ex[e] * invd;
        int s = src[e];
        float4 v = h[s * D4 + lane];
        acc.x += w * v.x; acc.y += w * v.y; acc.z += w * v.z; acc.w += w * v.w;
    }
    acc.x = fmaxf(acc.x, 0.f); acc.y = fmaxf(acc.y, 0.f);
    acc.z = fmaxf(acc.z, 0.f); acc.w = fmaxf(acc.w, 0.f);
    out[wid * D4 + lane] = acc;
}

// ---------------- launch -----------------------------------------------------

extern "C" void kernel_launch(void* const* d_in, const int* in_sizes, int n_in,
                              void* d_out, int out_size, void* d_ws, size_t ws_size,
                              hipStream_t stream) {
    const float* feats = (const float*)d_in[0];
    const int*   src   = (const int*)d_in[1];
    const int*   dst   = (const int*)d_in[2];
    const float* betas = (const float*)d_in[3];
    float* out = (float*)d_out;

    float* hA     = (float*)d_ws;              // NN*D floats
    float* hB     = hA + NN * D;               // NN*D floats
    float* inv    = hB + NN * D;               // NN floats
    float* ex     = inv + NN;                  // NE floats
    int*   rowptr = (int*)(ex + NE);           // NN+1 ints
    int*   cnt    = rowptr + (NN + 1);         // NN ints
    int*   eidx   = cnt + NN;                  // NE ints

    // CSR build (graph identical for all 4 layers)
    hipMemsetAsync(cnt, 0, NN * sizeof(int), stream);
    hist_kernel<<<(NE + 255) / 256, 256, 0, stream>>>(dst, cnt, NE);
    scan_kernel<<<1, 256, 0, stream>>>(cnt, rowptr, NN);
    hipMemsetAsync(cnt, 0, NN * sizeof(int), stream);
    scatter_kernel<<<(NE + 255) / 256, 256, 0, stream>>>(dst, rowptr, cnt, eidx, NE);

    const int node_blocks = (NN * 64 + 255) / 256;   // wave per node
    const int edge_blocks = (NE * 64 + 255) / 256;   // wave per edge

    const float* hin = feats;
    for (int l = 0; l < 4; ++l) {
        float* hout = (l == 3) ? out : ((l & 1) ? hB : hA);
        norm_kernel<<<node_blocks, 256, 0, stream>>>((const float4*)hin, inv, NN);
        edge_kernel<<<edge_blocks, 256, 0, stream>>>((const float4*)hin, inv, src, dst,
                                                     betas, l, ex, NE);
        agg_kernel<<<node_blocks, 256, 0, stream>>>((const float4*)hin, ex, rowptr, eidx,
                                                    src, (float4*)hout, NN);
        hin = hout;
    }
}

// Round 2
// 255.173 us; speedup vs baseline: 2.5925x; 2.5925x over previous
//
#include <hip/hip_runtime.h>
#include <hip/hip_bf16.h>

#define NN 10000
#define NE 320000
#define D 256
#define D4 64   // float4 per node row

// ---------------- CSR build (once per call; graph is static across layers) ---

__global__ void hist_kernel(const int* __restrict__ dst, int* __restrict__ cnt, int nE) {
    int e = blockIdx.x * blockDim.x + threadIdx.x;
    if (e < nE) atomicAdd(&cnt[dst[e]], 1);
}

// single-block exclusive scan over NN counts -> rowptr[0..NN]
__global__ void scan_kernel(const int* __restrict__ cnt, int* __restrict__ rowptr, int n) {
    __shared__ int part[256];
    int t = threadIdx.x;
    int chunk = (n + 255) / 256;
    int b = t * chunk;
    int e = b + chunk; if (e > n) e = n;
    int s = 0;
    for (int i = b; i < e; ++i) s += cnt[i];
    part[t] = s;
    __syncthreads();
    if (t == 0) {
        int acc = 0;
        for (int i = 0; i < 256; ++i) { int v = part[i]; part[i] = acc; acc += v; }
    }
    __syncthreads();
    if (b < n) {
        int acc = part[t];
        for (int i = b; i < e; ++i) { rowptr[i] = acc; acc += cnt[i]; }
        if (e == n) rowptr[n] = acc;   // total == nE
    }
}

// write SOURCE ids (not edge ids) grouped by dst -> fully coalesced reads later
__global__ void scatter_src_kernel(const int* __restrict__ src, const int* __restrict__ dst,
                                   const int* __restrict__ rowptr, int* __restrict__ cnt,
                                   int* __restrict__ esrc, int nE) {
    int e = blockIdx.x * blockDim.x + threadIdx.x;
    if (e < nE) {
        int d = dst[e];
        int pos = rowptr[d] + atomicAdd(&cnt[d], 1);
        esrc[pos] = src[e];
    }
}

// ---------------- per-layer kernels -----------------------------------------

// inv[n] = rsqrt(sum(h[n]^2) + 1e-16): one wave per node
__global__ void norm_kernel(const float4* __restrict__ h, float* __restrict__ inv, int n) {
    int wid  = (blockIdx.x * blockDim.x + threadIdx.x) >> 6;
    int lane = threadIdx.x & 63;
    if (wid >= n) return;
    float4 v = h[wid * D4 + lane];
    float s = v.x * v.x + v.y * v.y + v.z * v.z + v.w * v.w;
    #pragma unroll
    for (int o = 32; o; o >>= 1) s += __shfl_xor(s, o);
    if (lane == 0) inv[wid] = rsqrtf(s + 1e-16f);
}

// Fused: per dst node, read each h[src] row ONCE: dot, exp, accumulate.
// out[n] = relu( (sum_e ex_e h[src_e]) / (sum_e ex_e + eps) )
__global__ void fused_kernel(const float4* __restrict__ h, const float* __restrict__ inv,
                             const int* __restrict__ rowptr, const int* __restrict__ esrc,
                             const float* __restrict__ betas, int layer,
                             float4* __restrict__ out, int n) {
    int wid  = (blockIdx.x * blockDim.x + threadIdx.x) >> 6;
    int lane = threadIdx.x & 63;
    if (wid >= n) return;

    float4 a    = h[wid * D4 + lane];   // dst row, register-resident
    float  bivd = betas[layer] * inv[wid];
    int beg = rowptr[wid], end = rowptr[wid + 1];

    float4 acc = make_float4(0.f, 0.f, 0.f, 0.f);
    float dsum = 0.f;

    for (int base = beg; base < end; base += 64) {
        int idx = base + lane;
        int s_l = 0; float iv_l = 0.f;
        if (idx < end) { s_l = esrc[idx]; iv_l = inv[s_l]; }   // coalesced list + tiny gather
        int m = end - base; if (m > 64) m = 64;

        int t = 0;
        // 2-way pipelined over edges for ILP across the shuffle-reduce chains
        for (; t + 1 < m; t += 2) {
            int   s0 = __shfl(s_l, t),     s1 = __shfl(s_l, t + 1);
            float i0 = __shfl(iv_l, t),    i1 = __shfl(iv_l, t + 1);
            float4 v0 = h[s0 * D4 + lane];
            float4 v1 = h[s1 * D4 + lane];
            float p0 = a.x * v0.x + a.y * v0.y + a.z * v0.z + a.w * v0.w;
            float p1 = a.x * v1.x + a.y * v1.y + a.z * v1.z + a.w * v1.w;
            #pragma unroll
            for (int o = 32; o; o >>= 1) {
                p0 += __shfl_xor(p0, o);
                p1 += __shfl_xor(p1, o);
            }
            float e0 = __expf(p0 * bivd * i0);
            float e1 = __expf(p1 * bivd * i1);
            dsum += e0 + e1;
            acc.x += e0 * v0.x + e1 * v1.x;
            acc.y += e0 * v0.y + e1 * v1.y;
            acc.z += e0 * v0.z + e1 * v1.z;
            acc.w += e0 * v0.w + e1 * v1.w;
        }
        for (; t < m; ++t) {
            int   s0 = __shfl(s_l, t);
            float i0 = __shfl(iv_l, t);
            float4 v0 = h[s0 * D4 + lane];
            float p0 = a.x * v0.x + a.y * v0.y + a.z * v0.z + a.w * v0.w;
            #pragma unroll
            for (int o = 32; o; o >>= 1) p0 += __shfl_xor(p0, o);
            float e0 = __expf(p0 * bivd * i0);
            dsum += e0;
            acc.x += e0 * v0.x; acc.y += e0 * v0.y;
            acc.z += e0 * v0.z; acc.w += e0 * v0.w;
        }
    }

    float r = 1.f / (dsum + 1e-16f);
    acc.x = fmaxf(acc.x * r, 0.f); acc.y = fmaxf(acc.y * r, 0.f);
    acc.z = fmaxf(acc.z * r, 0.f); acc.w = fmaxf(acc.w * r, 0.f);
    out[wid * D4 + lane] = acc;
}

// ---------------- launch -----------------------------------------------------

extern "C" void kernel_launch(void* const* d_in, const int* in_sizes, int n_in,
                              void* d_out, int out_size, void* d_ws, size_t ws_size,
                              hipStream_t stream) {
    const float* feats = (const float*)d_in[0];
    const int*   src   = (const int*)d_in[1];
    const int*   dst   = (const int*)d_in[2];
    const float* betas = (const float*)d_in[3];
    float* out = (float*)d_out;

    float* hA     = (float*)d_ws;              // NN*D floats
    float* hB     = hA + NN * D;               // NN*D floats
    float* inv    = hB + NN * D;               // NN floats
    int*   rowptr = (int*)(inv + NN);          // NN+1 ints
    int*   cnt    = rowptr + (NN + 1);         // NN ints
    int*   esrc   = cnt + NN;                  // NE ints

    // CSR build (graph identical for all 4 layers)
    hipMemsetAsync(cnt, 0, NN * sizeof(int), stream);
    hist_kernel<<<(NE + 255) / 256, 256, 0, stream>>>(dst, cnt, NE);
    scan_kernel<<<1, 256, 0, stream>>>(cnt, rowptr, NN);
    hipMemsetAsync(cnt, 0, NN * sizeof(int), stream);
    scatter_src_kernel<<<(NE + 255) / 256, 256, 0, stream>>>(src, dst, rowptr, cnt, esrc, NE);

    const int node_blocks = (NN * 64 + 255) / 256;   // wave per node

    const float* hin = feats;
    for (int l = 0; l < 4; ++l) {
        float* hout = (l == 3) ? out : ((l & 1) ? hB : hA);
        norm_kernel<<<node_blocks, 256, 0, stream>>>((const float4*)hin, inv, NN);
        fused_kernel<<<node_blocks, 256, 0, stream>>>((const float4*)hin, inv, rowptr, esrc,
                                                      betas, l, (float4*)hout, NN);
        hin = hout;
    }
}